// Round 14
// baseline (1135.539 us; speedup 1.0000x reference)
//
#include <hip/hip_runtime.h>

#define SLEN 400
#define BATCH 32
#define TLEN 16
#define NDEC 15
#define EDIM 128
#define HDIM 256
#define H3 768
#define VVOC 50000
#define VEXT 50020
#define SCHUNK 50

// ---------- fast math helpers ----------
__device__ __forceinline__ float frcp(float x){ return __builtin_amdgcn_rcpf(x); }
__device__ __forceinline__ float fsig(float x){ return frcp(1.f + __expf(-x)); }
__device__ __forceinline__ float ftanh(float x){
  float e = __expf(2.f*x);
  return 1.f - 2.f*frcp(e + 1.f);
}

typedef _Float16 h2 __attribute__((ext_vector_type(2)));
typedef _Float16 half8 __attribute__((ext_vector_type(8)));
typedef float floatx4 __attribute__((ext_vector_type(4)));

__device__ __forceinline__ h2 u2h(unsigned u){ return __builtin_bit_cast(h2, u); }
__device__ __forceinline__ unsigned pkh(float a, float b){
  h2 v; v.x=(_Float16)a; v.y=(_Float16)b;
  return __builtin_bit_cast(unsigned, v);
}

#if __has_builtin(__builtin_amdgcn_fdot2)
__device__ __forceinline__ float fdot2h(h2 a, h2 b, float c){
  return __builtin_amdgcn_fdot2(a, b, c, false);
}
#else
__device__ __forceinline__ float fdot2h(h2 a, h2 b, float c){
  return fmaf((float)a.x,(float)b.x, fmaf((float)a.y,(float)b.y, c));
}
#endif

// i8 dot4: c += sum of 4 signed-i8 products (HW v_dot4_i32_i8 on CDNA)
#if __has_builtin(__builtin_amdgcn_sdot4)
__device__ __forceinline__ int sdot4(unsigned a, unsigned b, int c){
  return __builtin_amdgcn_sdot4((int)a, (int)b, c, false);
}
#else
__device__ __forceinline__ int sdot4(unsigned a, unsigned b, int c){
  #pragma unroll
  for (int k=0;k<4;++k)
    c += (int)(char)((a>>(8*k))&0xFF) * (int)(char)((b>>(8*k))&0xFF);
  return c;
}
#endif

__device__ __forceinline__ float wred_sum(float v){
  #pragma unroll
  for (int o=32;o>0;o>>=1) v += __shfl_down(v,o,64);
  return v;
}
__device__ __forceinline__ float wred_max(float v){
  #pragma unroll
  for (int o=32;o>0;o>>=1) v = fmaxf(v, __shfl_down(v,o,64));
  return v;
}
__device__ __forceinline__ float block_sum(float v, float* red){
  v = wred_sum(v);
  int lane = threadIdx.x & 63, wid = threadIdx.x >> 6;
  if (!lane) red[wid] = v;
  __syncthreads();
  if (threadIdx.x == 0){
    float m = red[0];
    int nw = blockDim.x >> 6;
    for (int w=1;w<nw;++w) m += red[w];
    red[0] = m;
  }
  __syncthreads();
  v = red[0];
  __syncthreads();
  return v;
}

// ---------- embedding gather ----------
__global__ __launch_bounds__(64) void k_embed(
    const int* __restrict__ input_seq, const int* __restrict__ target_seq,
    const float* __restrict__ embedding,
    _Float16* __restrict__ emb16, float* __restrict__ cat_all, _Float16* __restrict__ cat16)
{
  int row = blockIdx.x;
  if (row < SLEN*BATCH) {
    int s = row >> 5, b = row & 31;
    int tok = input_seq[b*SLEN + s];
    float2 v = ((const float2*)(embedding + (size_t)tok*EDIM))[threadIdx.x];
    ((unsigned*)(emb16 + (size_t)row*EDIM))[threadIdx.x] = pkh(v.x, v.y);
  } else {
    int rr = row - SLEN*BATCH;
    int t = rr >> 5, b = rr & 31;
    int tok = target_seq[b*TLEN + t];       // toks = target_seq[:, :T-1].T
    float2 v = ((const float2*)(embedding + (size_t)tok*EDIM))[threadIdx.x];
    ((float2*)(cat_all + (size_t)rr*896))[threadIdx.x] = v;       // cat cols [0:128) = e
    ((unsigned*)(cat16 + (size_t)rr*896))[threadIdx.x] = pkh(v.x, v.y);
  }
}

// ---------- batched flat fp32 -> f16 converts (5 jobs in one launch) ----------
__global__ __launch_bounds__(256) void k_cvtv5(
    const float* __restrict__ S0, _Float16* __restrict__ D0, int n0,
    const float* __restrict__ S1, _Float16* __restrict__ D1, int n1,
    const float* __restrict__ S2, _Float16* __restrict__ D2, int n2,
    const float* __restrict__ S3, _Float16* __restrict__ D3, int n3,
    const float* __restrict__ S4, _Float16* __restrict__ D4, int n4)
{
  const float* S; _Float16* D; int n8;
  switch (blockIdx.y){
    case 0: S=S0; D=D0; n8=n0; break;
    case 1: S=S1; D=D1; n8=n1; break;
    case 2: S=S2; D=D2; n8=n2; break;
    case 3: S=S3; D=D3; n8=n3; break;
    default: S=S4; D=D4; n8=n4; break;
  }
  int i = blockIdx.x*256 + threadIdx.x;
  if (i >= n8) return;
  float4 a = ((const float4*)S)[i*2];
  float4 b = ((const float4*)S)[i*2+1];
  uint4 o;
  o.x = pkh(a.x,a.y); o.y = pkh(a.z,a.w);
  o.z = pkh(b.x,b.y); o.w = pkh(b.z,b.w);
  ((uint4*)D)[i] = o;
}

// ---------- batched k-major f16 packers (3 jobs) ----------
__global__ __launch_bounds__(64) void k_cvtk3(
    const float* __restrict__ W0, uint4* __restrict__ D0,
    const float* __restrict__ W1, uint4* __restrict__ D1,
    const float* __restrict__ W2, uint4* __restrict__ D2)
{
  const float* W; uint4* D; int ldw, coloff, nrows, nk8;
  switch (blockIdx.y){
    case 0: W=W0; D=D0; ldw=640;  coloff=128; nrows=H3;   nk8=64; break;  // dec_Wih ctx cols
    case 1: W=W1; D=D1; ldw=HDIM; coloff=0;   nrows=H3;   nk8=32; break;  // dec_Whh
    default: W=W2; D=D2; ldw=HDIM; coloff=0;  nrows=HDIM; nk8=32; break;  // attn_Wq
  }
  int row = blockIdx.x, k8 = threadIdx.x;
  if (row >= nrows || k8 >= nk8) return;
  const float* s = W + (size_t)row*ldw + coloff + k8*8;
  float4 x = *(const float4*)s;
  float4 y = *(const float4*)(s+4);
  uint4 o;
  o.x = pkh(x.x,x.y); o.y = pkh(x.z,x.w);
  o.z = pkh(y.x,y.y); o.w = pkh(y.z,y.w);
  D[(size_t)k8*nrows + row] = o;
}

// ---------- i8 pack of full enc Whh rows, per-row scale ----------
__global__ __launch_bounds__(64) void k_cvti8(
    const float* __restrict__ Wf, uint4* __restrict__ Df,
    const float* __restrict__ Wb, uint4* __restrict__ Db,
    float* __restrict__ scl)
{
  int row = blockIdx.x, dir = blockIdx.y;
  const float* W = dir ? Wb : Wf;
  uint4* D = dir ? Db : Df;
  int t = threadIdx.x;
  const float* src = W + (size_t)row*HDIM;
  float m = 0.f;
  #pragma unroll
  for (int k=0;k<4;++k) m = fmaxf(m, fabsf(src[t*4+k]));
  m = wred_max(m);
  m = __shfl(m, 0, 64);
  float inv = (m > 0.f) ? 127.f/m : 0.f;
  if (t == 0) scl[dir*H3 + row] = (m > 0.f) ? m/(127.f*127.f) : 0.f;
  if (t < 16){
    unsigned u[4];
    #pragma unroll
    for (int q=0;q<4;++q){
      unsigned uu = 0;
      #pragma unroll
      for (int k=0;k<4;++k){
        int iv = (int)rintf(src[t*16 + q*4 + k]*inv);
        iv = iv > 127 ? 127 : (iv < -127 ? -127 : iv);
        uu |= ((unsigned)(iv & 0xFF)) << (8*k);
      }
      u[q] = uu;
    }
    uint4 o; o.x=u[0]; o.y=u[1]; o.z=u[2]; o.w=u[3];
    D[(size_t)t*H3 + row] = o;
  }
}

// ---------- MFMA f16 GEMM: C[m,n] = sum_k A16[am,k]*W16[n,k] + bias[n] ----------
// expsum != nullptr: epilogue also accumulates sum of exp(v) per row (atomicAdd).
__global__ __launch_bounds__(256) void k_gmm(
    const _Float16* __restrict__ A, int lda,
    const _Float16* __restrict__ W, int ldw,
    const float* __restrict__ bias,
    float* __restrict__ C, _Float16* __restrict__ C16, int ldc,
    int M, int N, int K, int rev, float* __restrict__ expsum)
{
  __shared__ __align__(16) _Float16 Al[128*64];
  __shared__ __align__(16) _Float16 Wl[128*64];
  int tid = threadIdx.x;
  int wv = tid >> 6, l = tid & 63;
  int wr = (wv>>1)*64, wc = (wv&1)*64;
  int lr = l & 15, lh = l >> 4;
  int m0 = blockIdx.y*128, n0 = blockIdx.x*128;
  floatx4 acc[4][4];
  #pragma unroll
  for (int i=0;i<4;++i)
    #pragma unroll
    for (int jn=0;jn<4;++jn) acc[i][jn] = (floatx4){0.f,0.f,0.f,0.f};

  for (int kc=0; kc<K; kc+=64){
    #pragma unroll
    for (int i=0;i<4;++i){
      int idx = tid + i*256;
      int row = idx>>3, c = idx&7;
      int m = m0+row;
      uint4 v = {0u,0u,0u,0u};
      if (m < M){
        int am = m;
        if (rev){ int s = m>>5; am = ((SLEN-1-s)<<5)|(m&31); }
        v = *(const uint4*)&A[(size_t)am*lda + kc + c*8];
      }
      *(uint4*)&Al[row*64 + ((c ^ (row&7))<<3)] = v;
    }
    #pragma unroll
    for (int i=0;i<4;++i){
      int idx = tid + i*256;
      int row = idx>>3, c = idx&7;
      int n = n0+row;
      uint4 v = {0u,0u,0u,0u};
      if (n < N) v = *(const uint4*)&W[(size_t)n*ldw + kc + c*8];
      *(uint4*)&Wl[row*64 + ((c ^ (row&7))<<3)] = v;
    }
    __syncthreads();
    #pragma unroll
    for (int ks=0; ks<2; ++ks){
      half8 af0, af1, af2, af3, bf0, bf1, bf2, bf3;
      {
        int c = ks*4 + lh;
        int r0 = wr + 0*16 + lr, r1 = wr + 1*16 + lr, r2 = wr + 2*16 + lr, r3 = wr + 3*16 + lr;
        af0 = *(const half8*)&Al[r0*64 + ((c ^ (r0&7))<<3)];
        af1 = *(const half8*)&Al[r1*64 + ((c ^ (r1&7))<<3)];
        af2 = *(const half8*)&Al[r2*64 + ((c ^ (r2&7))<<3)];
        af3 = *(const half8*)&Al[r3*64 + ((c ^ (r3&7))<<3)];
        int n0l = wc + 0*16 + lr, n1l = wc + 1*16 + lr, n2l = wc + 2*16 + lr, n3l = wc + 3*16 + lr;
        bf0 = *(const half8*)&Wl[n0l*64 + ((c ^ (n0l&7))<<3)];
        bf1 = *(const half8*)&Wl[n1l*64 + ((c ^ (n1l&7))<<3)];
        bf2 = *(const half8*)&Wl[n2l*64 + ((c ^ (n2l&7))<<3)];
        bf3 = *(const half8*)&Wl[n3l*64 + ((c ^ (n3l&7))<<3)];
      }
      half8 afs[4] = {af0, af1, af2, af3};
      half8 bfs[4] = {bf0, bf1, bf2, bf3};
      #pragma unroll
      for (int mi=0;mi<4;++mi)
        #pragma unroll
        for (int ni=0;ni<4;++ni)
          acc[mi][ni] = __builtin_amdgcn_mfma_f32_16x16x32_f16(afs[mi], bfs[ni], acc[mi][ni], 0,0,0);
    }
    __syncthreads();
  }
  #pragma unroll
  for (int mi=0;mi<4;++mi){
    #pragma unroll
    for (int q=0;q<4;++q){
      int m = m0 + wr + mi*16 + lh*4 + q;
      float psum = 0.f;
      if (m < M){
        #pragma unroll
        for (int ni=0;ni<4;++ni){
          int n = n0 + wc + ni*16 + lr;
          if (n < N){
            float v = acc[mi][ni][q] + bias[n];
            if (C)   C[(size_t)m*ldc + n] = v;
            if (C16) C16[(size_t)m*ldc + n] = (_Float16)v;
            if (expsum) psum += __expf(v);
          }
        }
      }
      if (expsum){
        #pragma unroll
        for (int o=8;o>0;o>>=1) psum += __shfl_down(psum, o, 16);
        if (lr == 0 && m < M) atomicAdd(&expsum[m], psum);
      }
    }
  }
}

// ---------- encoder GRU (structural floor ~412us) + out_W conversion on idle CUs ----------
// Blocks 0..63: all-i8 GRU recurrence (8 pairchunks LDS + 8 streamed).
// Blocks >=64: grid-stride fp32->f16 convert of out_W (runs on the 192 idle CUs).
__global__ __launch_bounds__(768) void k_enc(
    const _Float16* __restrict__ gi16_f, const _Float16* __restrict__ gi16_b,
    const uint4* __restrict__ Wi8_f, const uint4* __restrict__ Wi8_b,
    const float* __restrict__ scl_i8,
    const float* __restrict__ bhh_f, const float* __restrict__ bhh_b,
    _Float16* __restrict__ enc16, float* __restrict__ hfin,
    const float* __restrict__ outW, _Float16* __restrict__ outW16)
{
  if (blockIdx.x >= 64){
    int idx = (int)(blockIdx.x - 64)*768 + (int)threadIdx.x;
    const int stride = 200*768;
    for (int i = idx; i < 1600000; i += stride){
      float4 a = ((const float4*)outW)[i*2];
      float4 b2 = ((const float4*)outW)[i*2+1];
      uint4 o;
      o.x = pkh(a.x,a.y); o.y = pkh(a.z,a.w);
      o.z = pkh(b2.x,b2.y); o.w = pkh(b2.z,b2.w);
      ((uint4*)outW16)[i] = o;
    }
    return;
  }
  int dir = blockIdx.x >> 5, b = blockIdx.x & 31;
  int jj = threadIdx.x;
  const _Float16* gi = dir ? gi16_b : gi16_f;
  const uint4* Wi8p = (dir ? Wi8_b : Wi8_f) + jj;
  float scl = scl_i8[dir*H3 + jj];
  float bh = (dir ? bhh_b : bhh_f)[jj];

  __shared__ __align__(16) unsigned h8u[HDIM/4];   // i8-packed h*127 (256 B)
  __shared__ __align__(16) float st[H3];
  __shared__ uint4 Wlds[8][H3];                    // i8 pairchunks 0..7 (98304 B)

  #pragma unroll
  for (int p=0;p<8;++p) Wlds[p][jj] = Wi8p[p*H3];

  if (jj < HDIM/4) h8u[jj] = 0u;
  float hreg = 0.f;
  _Float16* dst = enc16 + (size_t)b*2*HDIM + dir*HDIM + jj;
  __syncthreads();

  for (int s=0;s<SLEN;++s){
    const _Float16* grow = gi + ((size_t)s*BATCH + b)*H3;
    float g1 = 0.f, g2 = 0.f;
    if (jj < 512)  g1 = (float)grow[jj];
    if (jj < HDIM) g2 = (float)grow[2*HDIM + jj];
    int is0=0, is1=0, is2=0, is3=0;
    #pragma unroll
    for (int p=0;p<8;++p){
      uint4 w = Wlds[p][jj];
      uint4 hq = *(const uint4*)&h8u[4*p];
      is0 = sdot4(w.x, hq.x, is0);
      is1 = sdot4(w.y, hq.y, is1);
      is2 = sdot4(w.z, hq.z, is2);
      is3 = sdot4(w.w, hq.w, is3);
    }
    #pragma unroll
    for (int p=8;p<16;++p){
      uint4 w = Wi8p[(size_t)p*H3];
      uint4 hq = *(const uint4*)&h8u[4*p];
      is0 = sdot4(w.x, hq.x, is0);
      is1 = sdot4(w.y, hq.y, is1);
      is2 = sdot4(w.z, hq.z, is2);
      is3 = sdot4(w.w, hq.w, is3);
    }
    float acc = (float)((is0+is1)+(is2+is3))*scl + bh;
    st[jj] = (jj < 512) ? (acc + g1) : acc;
    __syncthreads();
    if (jj < HDIM){
      float rr = fsig(st[jj]);
      float zz = fsig(st[HDIM + jj]);
      float nn = ftanh(g2 + rr*st[2*HDIM + jj]);
      float h2v = nn + zz*(hreg - nn);
      hreg = h2v;
      int srow = dir ? (SLEN-1-s) : s;
      dst[(size_t)srow*BATCH*2*HDIM] = (_Float16)h2v;
      int iv = (int)rintf(h2v*127.f);
      iv = iv > 127 ? 127 : (iv < -127 ? -127 : iv);
      ((char*)h8u)[jj] = (char)iv;
      if (s == SLEN-1) hfin[(size_t)(dir*BATCH + b)*HDIM + jj] = h2v;
    }
    __syncthreads();
  }
}

// ---------- bridge: h0 = tanh([hf,hb] @ bridge_W.T + b); also seed q_part for t=0 ----------
__global__ __launch_bounds__(256) void k_bridge(
    const float* __restrict__ hfin,
    const float* __restrict__ bridge_W, const float* __restrict__ bridge_b,
    const uint4* __restrict__ Wq16k,
    float* __restrict__ h_out, float* __restrict__ q_part)
{
  int b = blockIdx.x, j = threadIdx.x;
  __shared__ float hcat[2*HDIM];
  __shared__ float h0s[HDIM];
  hcat[j]        = hfin[(size_t)b*HDIM + j];
  hcat[HDIM + j] = hfin[(size_t)(BATCH + b)*HDIM + j];
  __syncthreads();
  const float* w = bridge_W + (size_t)j*2*HDIM;
  float4 a = {0.f,0.f,0.f,0.f};
  #pragma unroll 4
  for (int k=0;k<2*HDIM;k+=4){
    float4 h4 = *(const float4*)&hcat[k];
    float4 w4 = *(const float4*)&w[k];
    a.x=fmaf(h4.x,w4.x,a.x); a.y=fmaf(h4.y,w4.y,a.y);
    a.z=fmaf(h4.z,w4.z,a.z); a.w=fmaf(h4.w,w4.w,a.w);
  }
  float h0 = ftanh((a.x+a.y)+(a.z+a.w) + bridge_b[j]);
  h_out[b*HDIM+j] = h0;
  h0s[j] = h0;
  __syncthreads();
  // q_i = Wq row i . h0  -> slot 0; zero slots 1..7
  float qp = 0.f;
  #pragma unroll
  for (int k8=0;k8<32;++k8){
    uint4 wq = Wq16k[(size_t)k8*HDIM + j];
    const float* hb8 = &h0s[k8*8];
    h2 w0=u2h(wq.x), w1=u2h(wq.y), w2=u2h(wq.z), w3=u2h(wq.w);
    qp = fmaf((float)w0.x, hb8[0], qp); qp = fmaf((float)w0.y, hb8[1], qp);
    qp = fmaf((float)w1.x, hb8[2], qp); qp = fmaf((float)w1.y, hb8[3], qp);
    qp = fmaf((float)w2.x, hb8[4], qp); qp = fmaf((float)w2.y, hb8[5], qp);
    qp = fmaf((float)w3.x, hb8[6], qp); qp = fmaf((float)w3.y, hb8[7], qp);
  }
  q_part[((size_t)b*8 + 0)*HDIM + j] = qp;
  #pragma unroll
  for (int c=1;c<8;++c) q_part[((size_t)b*8 + c)*HDIM + j] = 0.f;
}

// ---------- decoder step part B: attention scores + e + partial sums/ctx ----------
// q comes pre-reduced from q_part (written by bridge/gruD) - no Wq traffic here.
__global__ __launch_bounds__(256) void k_attnB(
    int t,
    const _Float16* __restrict__ proj16,
    const _Float16* __restrict__ enc16,
    const float* __restrict__ q_part,
    const float* __restrict__ attn_We,
    float* __restrict__ alphas_e,
    float* __restrict__ sum_part,
    float* __restrict__ ctx_part)
{
  int ch = blockIdx.x, b = blockIdx.y;
  int tid = threadIdx.x;
  __shared__ float q_s[HDIM], we_s[HDIM], sc[SCHUNK], red[8];

  we_s[tid] = attn_We[tid];
  {
    float q = 0.f;
    #pragma unroll
    for (int c=0;c<8;++c) q += q_part[((size_t)b*8 + c)*HDIM + tid];
    q_s[tid] = q;
  }
  __syncthreads();
  {
    int wave = tid >> 6, lane = tid & 63;
    int d0 = lane*4;
    float4 qv = *(const float4*)&q_s[d0];
    float4 wv = *(const float4*)&we_s[d0];
    for (int is = wave; is < SCHUNK; is += 4){
      int s = ch*SCHUNK + is;
      uint2 p = *(const uint2*)&proj16[((size_t)(s*BATCH + b))*HDIM + d0];
      h2 pa = u2h(p.x), pb = u2h(p.y);
      float v = ftanh(qv.x+(float)pa.x)*wv.x + ftanh(qv.y+(float)pa.y)*wv.y
              + ftanh(qv.z+(float)pb.x)*wv.z + ftanh(qv.w+(float)pb.y)*wv.w;
      v = wred_sum(v);
      if (lane == 0){
        float e = __expf(v);
        sc[is] = e;
        alphas_e[((size_t)t*SLEN + s)*BATCH + b] = e;
      }
    }
  }
  __syncthreads();
  {
    float sv = (tid < SCHUNK) ? sc[tid] : 0.f;
    sv = block_sum(sv, red);
    if (tid == 0) sum_part[b*8 + ch] = sv;
  }
  {
    float a0=0.f, a1=0.f;
    for (int is=0; is<SCHUNK; ++is){
      int s = ch*SCHUNK + is;
      unsigned u = *(const unsigned*)&enc16[((size_t)(s*BATCH + b) << 9) + tid*2];
      h2 ev = u2h(u);
      float e = sc[is];
      a0 = fmaf(e, (float)ev.x, a0);
      a1 = fmaf(e, (float)ev.y, a1);
    }
    float2 o; o.x = a0; o.y = a1;
    *(float2*)&ctx_part[(((size_t)b*8 + ch) << 9) + tid*2] = o;
  }
}

// ---------- decoder step part D: ctx reduce + GRU + h/cat writes + q-partials for t+1 ----------
__global__ __launch_bounds__(256) void k_gruD(
    int t,
    const float* __restrict__ ctx_part,
    const float* __restrict__ sum_part,
    const float* __restrict__ gie_all,
    const uint4* __restrict__ dWck16,
    const uint4* __restrict__ dWhk16,
    const uint4* __restrict__ Wq16k,
    const float* __restrict__ dec_bhh,
    const float* __restrict__ hin,
    float* __restrict__ hout,
    float* __restrict__ cat_all, _Float16* __restrict__ cat16,
    float* __restrict__ sums_all, float* __restrict__ q_part)
{
  int ch = blockIdx.x, b = blockIdx.y;
  int tid = threadIdx.x;
  int jl = tid & 31, slice = tid >> 5;
  __shared__ __align__(16) unsigned cpk[HDIM], hpk[HDIM/2];
  __shared__ float hf[HDIM];
  __shared__ float pc[3][8][32], ph[3][8][32];
  __shared__ float hch[32];
  __shared__ float invs;

  if (tid == 0){
    float ssum = 0.f;
    #pragma unroll
    for (int c=0;c<8;++c) ssum += sum_part[b*8 + c];
    float inv = 1.f/ssum;
    invs = inv;
    if (ch == 0) sums_all[t*BATCH + b] = inv;
  }
  if (tid < HDIM/2){
    float2 hv = *(const float2*)&hin[b*HDIM + tid*2];
    hpk[tid] = pkh(hv.x, hv.y);
    hf[tid*2] = hv.x; hf[tid*2+1] = hv.y;
  }
  __syncthreads();
  {
    int d0 = tid*2;
    float c0=0.f, c1=0.f;
    #pragma unroll
    for (int c=0;c<8;++c){
      float2 v = *(const float2*)&ctx_part[(((size_t)b*8 + c) << 9) + d0];
      c0 += v.x; c1 += v.y;
    }
    c0 *= invs; c1 *= invs;
    cpk[tid] = pkh(c0, c1);
    if (ch == 0){
      int r = t*BATCH + b;
      cat_all[(size_t)r*896 + 384 + d0]     = c0;
      cat_all[(size_t)r*896 + 384 + d0 + 1] = c1;
      cat16[(size_t)r*896 + 384 + d0]     = (_Float16)c0;
      cat16[(size_t)r*896 + 384 + d0 + 1] = (_Float16)c1;
    }
  }
  __syncthreads();
  {
    int jb = ch*32 + jl;
    float c0=0.f,c1=0.f,c2=0.f, g0=0.f,g1=0.f,g2=0.f;
    #pragma unroll
    for (int i=0;i<8;++i){
      int k8 = slice*8 + i;
      uint4 hq = *(const uint4*)&cpk[k8*4];
      uint4 w0 = dWck16[(size_t)k8*H3 + jb];
      uint4 w1 = dWck16[(size_t)k8*H3 + 256 + jb];
      uint4 w2 = dWck16[(size_t)k8*H3 + 512 + jb];
      c0 = fdot2h(u2h(w0.x),u2h(hq.x),c0); c0 = fdot2h(u2h(w0.y),u2h(hq.y),c0);
      c0 = fdot2h(u2h(w0.z),u2h(hq.z),c0); c0 = fdot2h(u2h(w0.w),u2h(hq.w),c0);
      c1 = fdot2h(u2h(w1.x),u2h(hq.x),c1); c1 = fdot2h(u2h(w1.y),u2h(hq.y),c1);
      c1 = fdot2h(u2h(w1.z),u2h(hq.z),c1); c1 = fdot2h(u2h(w1.w),u2h(hq.w),c1);
      c2 = fdot2h(u2h(w2.x),u2h(hq.x),c2); c2 = fdot2h(u2h(w2.y),u2h(hq.y),c2);
      c2 = fdot2h(u2h(w2.z),u2h(hq.z),c2); c2 = fdot2h(u2h(w2.w),u2h(hq.w),c2);
    }
    #pragma unroll
    for (int i=0;i<4;++i){
      int k8 = slice*4 + i;
      uint4 hq = *(const uint4*)&hpk[k8*4];
      uint4 w0 = dWhk16[(size_t)k8*H3 + jb];
      uint4 w1 = dWhk16[(size_t)k8*H3 + 256 + jb];
      uint4 w2 = dWhk16[(size_t)k8*H3 + 512 + jb];
      g0 = fdot2h(u2h(w0.x),u2h(hq.x),g0); g0 = fdot2h(u2h(w0.y),u2h(hq.y),g0);
      g0 = fdot2h(u2h(w0.z),u2h(hq.z),g0); g0 = fdot2h(u2h(w0.w),u2h(hq.w),g0);
      g1 = fdot2h(u2h(w1.x),u2h(hq.x),g1); g1 = fdot2h(u2h(w1.y),u2h(hq.y),g1);
      g1 = fdot2h(u2h(w1.z),u2h(hq.z),g1); g1 = fdot2h(u2h(w1.w),u2h(hq.w),g1);
      g2 = fdot2h(u2h(w2.x),u2h(hq.x),g2); g2 = fdot2h(u2h(w2.y),u2h(hq.y),g2);
      g2 = fdot2h(u2h(w2.z),u2h(hq.z),g2); g2 = fdot2h(u2h(w2.w),u2h(hq.w),g2);
    }
    pc[0][slice][jl]=c0; pc[1][slice][jl]=c1; pc[2][slice][jl]=c2;
    ph[0][slice][jl]=g0; ph[1][slice][jl]=g1; ph[2][slice][jl]=g2;
  }
  __syncthreads();
  if (tid < 32){
    int j = tid, r = t*BATCH + b;
    int jj = ch*32 + j;
    float gi0 = gie_all[(size_t)r*H3 + jj];
    float gi1 = gie_all[(size_t)r*H3 + 256 + jj];
    float gi2 = gie_all[(size_t)r*H3 + 512 + jj];
    float gh0 = dec_bhh[jj], gh1 = dec_bhh[256 + jj], gh2 = dec_bhh[512 + jj];
    #pragma unroll
    for (int c=0;c<8;++c){
      gi0 += pc[0][c][j]; gi1 += pc[1][c][j]; gi2 += pc[2][c][j];
      gh0 += ph[0][c][j]; gh1 += ph[1][c][j]; gh2 += ph[2][c][j];
    }
    float rr = fsig(gi0 + gh0);
    float zz = fsig(gi1 + gh1);
    float nn = ftanh(gi2 + rr*gh2);
    float hp = hf[jj];
    float h2v = nn + zz*(hp - nn);
    hout[b*HDIM + jj] = h2v;
    cat_all[(size_t)r*896 + 128 + jj] = h2v;
    cat16[(size_t)r*896 + 128 + jj] = (_Float16)h2v;
    hch[j] = h2v;
  }
  __syncthreads();
  // q-partial for step t+1: this block's 32-element h chunk x Wq columns
  {
    float qp = 0.f;
    #pragma unroll
    for (int kk=0; kk<4; ++kk){
      uint4 wq = Wq16k[(size_t)(ch*4+kk)*HDIM + tid];
      const float* hb8 = &hch[kk*8];
      h2 w0=u2h(wq.x), w1=u2h(wq.y), w2=u2h(wq.z), w3=u2h(wq.w);
      qp = fmaf((float)w0.x, hb8[0], qp); qp = fmaf((float)w0.y, hb8[1], qp);
      qp = fmaf((float)w1.x, hb8[2], qp); qp = fmaf((float)w1.y, hb8[3], qp);
      qp = fmaf((float)w2.x, hb8[4], qp); qp = fmaf((float)w2.y, hb8[5], qp);
      qp = fmaf((float)w3.x, hb8[6], qp); qp = fmaf((float)w3.y, hb8[7], qp);
    }
    q_part[((size_t)b*8 + ch)*HDIM + tid] = qp;
  }
}

// ---------- p_gen = sigmoid(cat . pgen_W + b) ----------
__global__ __launch_bounds__(64) void k_pgen(
    const float* __restrict__ cat_all,
    const float* __restrict__ pgen_W, const float* __restrict__ pgen_b,
    float* __restrict__ pgen_all)
{
  int r = blockIdx.x;
  const float* c = cat_all + (size_t)r*896;
  float acc = 0.f;
  for (int k=threadIdx.x; k<896; k+=64) acc = fmaf(c[k], pgen_W[k], acc);
  acc = wred_sum(acc);
  if (threadIdx.x==0) pgen_all[r] = fsig(acc + pgen_b[0]);
}

// ---------- scatter copy-distribution into zeroed out (linear domain) ----------
__global__ __launch_bounds__(512) void k_scatter(
    const int* __restrict__ input_seq_ext,
    const float* __restrict__ alphas_e, const float* __restrict__ sums_all,
    const float* __restrict__ pgen_all,
    float* __restrict__ out)
{
  int r = blockIdx.x;               // t*32+b
  int s = threadIdx.x;
  if (s >= SLEN) return;
  int t = r >> 5, b = r & 31;
  float w = (1.f - pgen_all[r]) * alphas_e[((size_t)t*SLEN + s)*BATCH + b] * sums_all[r];
  int idx = input_seq_ext[b*SLEN + s];
  atomicAdd(&out[((size_t)(t+1)*BATCH + b)*VEXT + idx], w);
}

// ---------- fused final: out = log(copy + gen + 1e-12), t in [1,16) ----------
// row_sum holds SUM of exp(logits) (from the GEMM epilogue) -> invert here.
__global__ __launch_bounds__(256) void k_final2(
    const _Float16* __restrict__ logits, const float* __restrict__ pgen_all,
    const float* __restrict__ row_sum,
    float* __restrict__ out)
{
  int v = blockIdx.x*256 + threadIdx.x;
  if (v >= VEXT) return;
  int b = blockIdx.y, t = blockIdx.z + 1;
  size_t o = ((size_t)t*BATCH + b)*VEXT + v;
  int r = (t-1)*BATCH + b;
  float val = out[o] + 1e-12f;      // copy mass from k_scatter (0 elsewhere)
  if (v < VVOC)
    val += pgen_all[r] * frcp(row_sum[r]) * __expf((float)logits[(size_t)r*VVOC + v]);
  out[o] = __logf(val);
}

extern "C" void kernel_launch(void* const* d_in, const int* in_sizes, int n_in,
                              void* d_out, int out_size, void* d_ws, size_t ws_size,
                              hipStream_t stream)
{
  (void)in_sizes; (void)n_in; (void)ws_size;
  const int*   input_seq     = (const int*)d_in[0];
  const int*   input_seq_ext = (const int*)d_in[1];
  const int*   target_seq    = (const int*)d_in[2];
  const float* embedding     = (const float*)d_in[3];
  const float* enc_Wih_f     = (const float*)d_in[4];
  const float* enc_Whh_f     = (const float*)d_in[5];
  const float* enc_bih_f     = (const float*)d_in[6];
  const float* enc_bhh_f     = (const float*)d_in[7];
  const float* enc_Wih_b     = (const float*)d_in[8];
  const float* enc_Whh_b     = (const float*)d_in[9];
  const float* enc_bih_b     = (const float*)d_in[10];
  const float* enc_bhh_b     = (const float*)d_in[11];
  const float* proj_W        = (const float*)d_in[12];
  const float* proj_b        = (const float*)d_in[13];
  const float* bridge_W      = (const float*)d_in[14];
  const float* bridge_b      = (const float*)d_in[15];
  const float* dec_Wih       = (const float*)d_in[16];
  const float* dec_Whh       = (const float*)d_in[17];
  const float* dec_bih       = (const float*)d_in[18];
  const float* dec_bhh       = (const float*)d_in[19];
  const float* attn_Wq       = (const float*)d_in[20];
  const float* attn_We       = (const float*)d_in[21];
  const float* lin_W         = (const float*)d_in[22];
  const float* lin_b         = (const float*)d_in[23];
  const float* pgen_W        = (const float*)d_in[24];
  const float* pgen_b        = (const float*)d_in[25];
  const float* out_W         = (const float*)d_in[26];
  const float* out_b         = (const float*)d_in[27];
  float* out = (float*)d_out;
  float* ws  = (float*)d_ws;

  // ---- workspace layout (float offsets); ~146 MB
  _Float16* emb16    = (_Float16*)(ws + 0);            // 409600 f
  _Float16* Wih16_f  = (_Float16*)(ws + 409600);       // 49152 f
  _Float16* Wih16_b  = (_Float16*)(ws + 458752);       // 49152 f
  _Float16* proj_W16 = (_Float16*)(ws + 507904);       // 65536 f
  _Float16* lin_W16  = (_Float16*)(ws + 573440);       // 114688 f
  _Float16* cat16    = (_Float16*)(ws + 688128);       // 215040 f
  _Float16* lin16    = (_Float16*)(ws + 903168);       // 61440 f
  _Float16* dWih16   = (_Float16*)(ws + 964608);       // 245760 f -> 1210368
  _Float16* enc16    = (_Float16*)(ws + 1638400);      // 3276800 f
  float* hfin        = ws + 4915200;                   // 16384 f
  _Float16* proj16   = (_Float16*)(ws + 8192000);      // 1638400 f
  _Float16* gi16_f   = (_Float16*)(ws + 11468800);     // 4915200 f [dies after k_enc]
  _Float16* gi16_b   = (_Float16*)(ws + 16384000);     // 4915200 f [dies after k_enc]
  _Float16* logits16 = (_Float16*)(ws + 11468800);     // 6000000 f (post-enc, overlaps gi)
  _Float16* out_W16  = (_Float16*)(ws + 23468800);     // 6400000 f
  uint4* Wq16k       = (uint4*)(ws + 33145600);        // 32768 f
  uint4* dWck16      = (uint4*)(ws + 33178368);        // 196608 f
  uint4* dWhk16      = (uint4*)(ws + 33374976);        // 98304 f
  float* ctx_part    = ws + 33473280;                  // 131072 f
  float* sum_part    = ws + 33604352;                  // 256 f
  float* sums_all    = ws + 33604608;                  // 480 f
  float* hbuf0       = ws + 33605088;                  // 8192 f
  float* hbuf1       = ws + 33613280;                  // 8192 f -> 33621472
  uint4* Wi8_f       = (uint4*)(ws + 33621472);        // 49152 f (16 i8 pairchunks, dir f)
  uint4* Wi8_b       = (uint4*)(ws + 33670624);        // 49152 f
  float* scl_i8      = ws + 33719776;                  // 1536 f -> 33721312
  float* q_part      = ws + 33721312;                  // 65536 f -> 33786848
  float* cat_all     = ws + 35468800;                  // 430080
  float* gie_all     = ws + 35898880;                  // 368640
  float* alphas_e    = ws + 36275712;                  // 192000
  float* pgen_all    = ws + 36467712;                  // 480
  float* row_sum     = ws + 36468192;                  // 480

  // zero the output early (t=0 rows stay 0; scatter accumulates into zeros)
  (void)hipMemsetAsync(out, 0, (size_t)out_size*sizeof(float), stream);
  (void)hipMemsetAsync(row_sum, 0, 480*sizeof(float), stream);

  k_embed<<<dim3(SLEN*BATCH + NDEC*BATCH), dim3(64), 0, stream>>>(
      input_seq, target_seq, embedding, emb16, cat_all, cat16);

  // batched weight conversions
  k_cvtv5<<<dim3(240, 5), dim3(256), 0, stream>>>(
      enc_Wih_f, Wih16_f, 12288,
      enc_Wih_b, Wih16_b, 12288,
      proj_W,    proj_W16, 16384,
      lin_W,     lin_W16,  28672,
      dec_Wih,   dWih16,   61440);
  k_cvtk3<<<dim3(H3, 3), dim3(64), 0, stream>>>(
      dec_Wih,   dWck16,
      dec_Whh,   dWhk16,
      attn_Wq,   Wq16k);
  k_cvti8<<<dim3(H3, 2), dim3(64), 0, stream>>>(enc_Whh_f, Wi8_f, enc_Whh_b, Wi8_b, scl_i8);

  // gi (f16) = emb @ Wih.T + bih (MFMA)
  k_gmm<<<dim3(6,100), dim3(256), 0, stream>>>(emb16, EDIM, Wih16_f, EDIM, enc_bih_f,
      (float*)nullptr, gi16_f, H3, SLEN*BATCH, H3, EDIM, 0, (float*)nullptr);
  k_gmm<<<dim3(6,100), dim3(256), 0, stream>>>(emb16, EDIM, Wih16_b, EDIM, enc_bih_b,
      (float*)nullptr, gi16_b, H3, SLEN*BATCH, H3, EDIM, 1, (float*)nullptr);

  // k_enc: 64 recurrence blocks + 200 conversion blocks (out_W -> f16 on idle CUs)
  k_enc<<<dim3(264), dim3(768), 0, stream>>>(gi16_f, gi16_b, Wi8_f, Wi8_b,
      scl_i8, enc_bhh_f, enc_bhh_b, enc16, hfin, out_W, out_W16);

  // proj (f16) = enc16 @ proj_W.T + proj_b
  k_gmm<<<dim3(2,100), dim3(256), 0, stream>>>(enc16, 2*HDIM, proj_W16, 2*HDIM, proj_b,
      (float*)nullptr, proj16, HDIM, SLEN*BATCH, HDIM, 2*HDIM, 0, (float*)nullptr);

  k_bridge<<<dim3(BATCH), dim3(256), 0, stream>>>(hfin, bridge_W, bridge_b, Wq16k,
      hbuf0, q_part);

  // decoder-embedding gate contributions (K=128 e-cols of cat), MFMA
  k_gmm<<<dim3(6,4), dim3(256), 0, stream>>>(cat16, 896, dWih16, 640, dec_bih,
      gie_all, (_Float16*)nullptr, H3, NDEC*BATCH, H3, EDIM, 0, (float*)nullptr);

  // 15 decoder steps: 2 wide kernels per step, h ping-pong, q carried via q_part
  float* hb[2] = {hbuf0, hbuf1};
  for (int t=0;t<NDEC;++t){
    k_attnB<<<dim3(8,32), dim3(256), 0, stream>>>(t, proj16, enc16, q_part, attn_We,
        alphas_e, sum_part, ctx_part);
    k_gruD<<<dim3(8,32), dim3(256), 0, stream>>>(t, ctx_part, sum_part, gie_all,
        dWck16, dWhk16, Wq16k, dec_bhh, hb[t&1], hb[(t+1)&1], cat_all, cat16,
        sums_all, q_part);
  }

  // epilogue
  k_gmm<<<dim3(2,4), dim3(256), 0, stream>>>(cat16, 896, lin_W16, 896, lin_b,
      (float*)nullptr, lin16, HDIM, NDEC*BATCH, HDIM, 896, 0, (float*)nullptr);
  k_pgen<<<dim3(NDEC*BATCH), dim3(64), 0, stream>>>(cat_all, pgen_W, pgen_b, pgen_all);
  // logits GEMM with fused exp-sum epilogue (row_sum pre-zeroed)
  k_gmm<<<dim3(391,4), dim3(256), 0, stream>>>(lin16, HDIM, out_W16, HDIM, out_b,
      (float*)nullptr, logits16, VVOC, NDEC*BATCH, VVOC, HDIM, 0, row_sum);
  k_scatter<<<dim3(NDEC*BATCH), dim3(512), 0, stream>>>(input_seq_ext, alphas_e, sums_all, pgen_all, out);
  k_final2<<<dim3(196, BATCH, NDEC), dim3(256), 0, stream>>>(logits16, pgen_all, row_sum, out);
}

// Round 15
// 1020.489 us; speedup vs baseline: 1.1127x; 1.1127x over previous
//
#include <hip/hip_runtime.h>

#define SLEN 400
#define BATCH 32
#define TLEN 16
#define NDEC 15
#define EDIM 128
#define HDIM 256
#define H3 768
#define VVOC 50000
#define VEXT 50020
#define SCHUNK 50

// ---------- fast math helpers ----------
__device__ __forceinline__ float frcp(float x){ return __builtin_amdgcn_rcpf(x); }
__device__ __forceinline__ float fsig(float x){ return frcp(1.f + __expf(-x)); }
__device__ __forceinline__ float ftanh(float x){
  float e = __expf(2.f*x);
  return 1.f - 2.f*frcp(e + 1.f);
}

typedef _Float16 h2 __attribute__((ext_vector_type(2)));
typedef _Float16 half8 __attribute__((ext_vector_type(8)));
typedef float floatx4 __attribute__((ext_vector_type(4)));

__device__ __forceinline__ h2 u2h(unsigned u){ return __builtin_bit_cast(h2, u); }
__device__ __forceinline__ unsigned pkh(float a, float b){
  h2 v; v.x=(_Float16)a; v.y=(_Float16)b;
  return __builtin_bit_cast(unsigned, v);
}

#if __has_builtin(__builtin_amdgcn_fdot2)
__device__ __forceinline__ float fdot2h(h2 a, h2 b, float c){
  return __builtin_amdgcn_fdot2(a, b, c, false);
}
#else
__device__ __forceinline__ float fdot2h(h2 a, h2 b, float c){
  return fmaf((float)a.x,(float)b.x, fmaf((float)a.y,(float)b.y, c));
}
#endif

// i8 dot4: c += sum of 4 signed-i8 products (HW v_dot4_i32_i8 on CDNA)
#if __has_builtin(__builtin_amdgcn_sdot4)
__device__ __forceinline__ int sdot4(unsigned a, unsigned b, int c){
  return __builtin_amdgcn_sdot4((int)a, (int)b, c, false);
}
#else
__device__ __forceinline__ int sdot4(unsigned a, unsigned b, int c){
  #pragma unroll
  for (int k=0;k<4;++k)
    c += (int)(char)((a>>(8*k))&0xFF) * (int)(char)((b>>(8*k))&0xFF);
  return c;
}
#endif

__device__ __forceinline__ float wred_sum(float v){
  #pragma unroll
  for (int o=32;o>0;o>>=1) v += __shfl_down(v,o,64);
  return v;
}
__device__ __forceinline__ float wred_max(float v){
  #pragma unroll
  for (int o=32;o>0;o>>=1) v = fmaxf(v, __shfl_down(v,o,64));
  return v;
}
__device__ __forceinline__ float block_sum(float v, float* red){
  v = wred_sum(v);
  int lane = threadIdx.x & 63, wid = threadIdx.x >> 6;
  if (!lane) red[wid] = v;
  __syncthreads();
  if (threadIdx.x == 0){
    float m = red[0];
    int nw = blockDim.x >> 6;
    for (int w=1;w<nw;++w) m += red[w];
    red[0] = m;
  }
  __syncthreads();
  v = red[0];
  __syncthreads();
  return v;
}

// ---------- embedding gather ----------
__global__ __launch_bounds__(64) void k_embed(
    const int* __restrict__ input_seq, const int* __restrict__ target_seq,
    const float* __restrict__ embedding,
    _Float16* __restrict__ emb16, float* __restrict__ cat_all, _Float16* __restrict__ cat16)
{
  int row = blockIdx.x;
  if (row < SLEN*BATCH) {
    int s = row >> 5, b = row & 31;
    int tok = input_seq[b*SLEN + s];
    float2 v = ((const float2*)(embedding + (size_t)tok*EDIM))[threadIdx.x];
    ((unsigned*)(emb16 + (size_t)row*EDIM))[threadIdx.x] = pkh(v.x, v.y);
  } else {
    int rr = row - SLEN*BATCH;
    int t = rr >> 5, b = rr & 31;
    int tok = target_seq[b*TLEN + t];       // toks = target_seq[:, :T-1].T
    float2 v = ((const float2*)(embedding + (size_t)tok*EDIM))[threadIdx.x];
    ((float2*)(cat_all + (size_t)rr*896))[threadIdx.x] = v;       // cat cols [0:128) = e
    ((unsigned*)(cat16 + (size_t)rr*896))[threadIdx.x] = pkh(v.x, v.y);
  }
}

// ---------- batched flat fp32 -> f16 converts (5 jobs in one launch) ----------
__global__ __launch_bounds__(256) void k_cvtv5(
    const float* __restrict__ S0, _Float16* __restrict__ D0, int n0,
    const float* __restrict__ S1, _Float16* __restrict__ D1, int n1,
    const float* __restrict__ S2, _Float16* __restrict__ D2, int n2,
    const float* __restrict__ S3, _Float16* __restrict__ D3, int n3,
    const float* __restrict__ S4, _Float16* __restrict__ D4, int n4)
{
  const float* S; _Float16* D; int n8;
  switch (blockIdx.y){
    case 0: S=S0; D=D0; n8=n0; break;
    case 1: S=S1; D=D1; n8=n1; break;
    case 2: S=S2; D=D2; n8=n2; break;
    case 3: S=S3; D=D3; n8=n3; break;
    default: S=S4; D=D4; n8=n4; break;
  }
  int i = blockIdx.x*256 + threadIdx.x;
  if (i >= n8) return;
  float4 a = ((const float4*)S)[i*2];
  float4 b = ((const float4*)S)[i*2+1];
  uint4 o;
  o.x = pkh(a.x,a.y); o.y = pkh(a.z,a.w);
  o.z = pkh(b.x,b.y); o.w = pkh(b.z,b.w);
  ((uint4*)D)[i] = o;
}

// ---------- batched k-major f16 packers (3 jobs) ----------
__global__ __launch_bounds__(64) void k_cvtk3(
    const float* __restrict__ W0, uint4* __restrict__ D0,
    const float* __restrict__ W1, uint4* __restrict__ D1,
    const float* __restrict__ W2, uint4* __restrict__ D2)
{
  const float* W; uint4* D; int ldw, coloff, nrows, nk8;
  switch (blockIdx.y){
    case 0: W=W0; D=D0; ldw=640;  coloff=128; nrows=H3;   nk8=64; break;  // dec_Wih ctx cols
    case 1: W=W1; D=D1; ldw=HDIM; coloff=0;   nrows=H3;   nk8=32; break;  // dec_Whh
    default: W=W2; D=D2; ldw=HDIM; coloff=0;  nrows=HDIM; nk8=32; break;  // attn_Wq
  }
  int row = blockIdx.x, k8 = threadIdx.x;
  if (row >= nrows || k8 >= nk8) return;
  const float* s = W + (size_t)row*ldw + coloff + k8*8;
  float4 x = *(const float4*)s;
  float4 y = *(const float4*)(s+4);
  uint4 o;
  o.x = pkh(x.x,x.y); o.y = pkh(x.z,x.w);
  o.z = pkh(y.x,y.y); o.w = pkh(y.z,y.w);
  D[(size_t)k8*nrows + row] = o;
}

// ---------- i8 pack of full enc Whh rows, per-row scale ----------
// Pairchunk layout: D[p*H3 + row] = uint4 of 16 i8 = k in [16p, 16p+16), p in [0,16).
// scl[dir*H3+row] = rowmax/(127*127): dequant factor (h scaled by 127).
__global__ __launch_bounds__(64) void k_cvti8(
    const float* __restrict__ Wf, uint4* __restrict__ Df,
    const float* __restrict__ Wb, uint4* __restrict__ Db,
    float* __restrict__ scl)
{
  int row = blockIdx.x, dir = blockIdx.y;
  const float* W = dir ? Wb : Wf;
  uint4* D = dir ? Db : Df;
  int t = threadIdx.x;
  const float* src = W + (size_t)row*HDIM;
  float m = 0.f;
  #pragma unroll
  for (int k=0;k<4;++k) m = fmaxf(m, fabsf(src[t*4+k]));
  m = wred_max(m);
  m = __shfl(m, 0, 64);
  float inv = (m > 0.f) ? 127.f/m : 0.f;
  if (t == 0) scl[dir*H3 + row] = (m > 0.f) ? m/(127.f*127.f) : 0.f;
  if (t < 16){
    unsigned u[4];
    #pragma unroll
    for (int q=0;q<4;++q){
      unsigned uu = 0;
      #pragma unroll
      for (int k=0;k<4;++k){
        int iv = (int)rintf(src[t*16 + q*4 + k]*inv);
        iv = iv > 127 ? 127 : (iv < -127 ? -127 : iv);
        uu |= ((unsigned)(iv & 0xFF)) << (8*k);
      }
      u[q] = uu;
    }
    uint4 o; o.x=u[0]; o.y=u[1]; o.z=u[2]; o.w=u[3];
    D[(size_t)t*H3 + row] = o;
  }
}

// ---------- MFMA f16 GEMM: C[m,n] = sum_k A16[am,k]*W16[n,k] + bias[n] ----------
__global__ __launch_bounds__(256) void k_gmm(
    const _Float16* __restrict__ A, int lda,
    const _Float16* __restrict__ W, int ldw,
    const float* __restrict__ bias,
    float* __restrict__ C, _Float16* __restrict__ C16, int ldc,
    int M, int N, int K, int rev)
{
  __shared__ __align__(16) _Float16 Al[128*64];
  __shared__ __align__(16) _Float16 Wl[128*64];
  int tid = threadIdx.x;
  int wv = tid >> 6, l = tid & 63;
  int wr = (wv>>1)*64, wc = (wv&1)*64;
  int lr = l & 15, lh = l >> 4;
  int m0 = blockIdx.y*128, n0 = blockIdx.x*128;
  floatx4 acc[4][4];
  #pragma unroll
  for (int i=0;i<4;++i)
    #pragma unroll
    for (int jn=0;jn<4;++jn) acc[i][jn] = (floatx4){0.f,0.f,0.f,0.f};

  for (int kc=0; kc<K; kc+=64){
    #pragma unroll
    for (int i=0;i<4;++i){
      int idx = tid + i*256;
      int row = idx>>3, c = idx&7;
      int m = m0+row;
      uint4 v = {0u,0u,0u,0u};
      if (m < M){
        int am = m;
        if (rev){ int s = m>>5; am = ((SLEN-1-s)<<5)|(m&31); }
        v = *(const uint4*)&A[(size_t)am*lda + kc + c*8];
      }
      *(uint4*)&Al[row*64 + ((c ^ (row&7))<<3)] = v;
    }
    #pragma unroll
    for (int i=0;i<4;++i){
      int idx = tid + i*256;
      int row = idx>>3, c = idx&7;
      int n = n0+row;
      uint4 v = {0u,0u,0u,0u};
      if (n < N) v = *(const uint4*)&W[(size_t)n*ldw + kc + c*8];
      *(uint4*)&Wl[row*64 + ((c ^ (row&7))<<3)] = v;
    }
    __syncthreads();
    #pragma unroll
    for (int ks=0; ks<2; ++ks){
      half8 af0, af1, af2, af3, bf0, bf1, bf2, bf3;
      {
        int c = ks*4 + lh;
        int r0 = wr + 0*16 + lr, r1 = wr + 1*16 + lr, r2 = wr + 2*16 + lr, r3 = wr + 3*16 + lr;
        af0 = *(const half8*)&Al[r0*64 + ((c ^ (r0&7))<<3)];
        af1 = *(const half8*)&Al[r1*64 + ((c ^ (r1&7))<<3)];
        af2 = *(const half8*)&Al[r2*64 + ((c ^ (r2&7))<<3)];
        af3 = *(const half8*)&Al[r3*64 + ((c ^ (r3&7))<<3)];
        int n0l = wc + 0*16 + lr, n1l = wc + 1*16 + lr, n2l = wc + 2*16 + lr, n3l = wc + 3*16 + lr;
        bf0 = *(const half8*)&Wl[n0l*64 + ((c ^ (n0l&7))<<3)];
        bf1 = *(const half8*)&Wl[n1l*64 + ((c ^ (n1l&7))<<3)];
        bf2 = *(const half8*)&Wl[n2l*64 + ((c ^ (n2l&7))<<3)];
        bf3 = *(const half8*)&Wl[n3l*64 + ((c ^ (n3l&7))<<3)];
      }
      half8 afs[4] = {af0, af1, af2, af3};
      half8 bfs[4] = {bf0, bf1, bf2, bf3};
      #pragma unroll
      for (int mi=0;mi<4;++mi)
        #pragma unroll
        for (int ni=0;ni<4;++ni)
          acc[mi][ni] = __builtin_amdgcn_mfma_f32_16x16x32_f16(afs[mi], bfs[ni], acc[mi][ni], 0,0,0);
    }
    __syncthreads();
  }
  #pragma unroll
  for (int mi=0;mi<4;++mi){
    #pragma unroll
    for (int q=0;q<4;++q){
      int m = m0 + wr + mi*16 + lh*4 + q;
      if (m < M){
        #pragma unroll
        for (int ni=0;ni<4;++ni){
          int n = n0 + wc + ni*16 + lr;
          if (n < N){
            float v = acc[mi][ni][q] + bias[n];
            if (C)   C[(size_t)m*ldc + n] = v;
            if (C16) C16[(size_t)m*ldc + n] = (_Float16)v;
          }
        }
      }
    }
  }
}

// ---------- encoder GRU (structural floor ~412us) + out_W conversion on idle CUs ----------
// Blocks 0..63: all-i8 GRU recurrence (8 pairchunks LDS + 8 streamed).
// Blocks >=64: grid-stride fp32->f16 convert of out_W (runs on the 192 idle CUs).
__global__ __launch_bounds__(768) void k_enc(
    const _Float16* __restrict__ gi16_f, const _Float16* __restrict__ gi16_b,
    const uint4* __restrict__ Wi8_f, const uint4* __restrict__ Wi8_b,
    const float* __restrict__ scl_i8,
    const float* __restrict__ bhh_f, const float* __restrict__ bhh_b,
    _Float16* __restrict__ enc16, float* __restrict__ hfin,
    const float* __restrict__ outW, _Float16* __restrict__ outW16)
{
  if (blockIdx.x >= 64){
    int idx = (int)(blockIdx.x - 64)*768 + (int)threadIdx.x;
    const int stride = 200*768;
    for (int i = idx; i < 1600000; i += stride){
      float4 a = ((const float4*)outW)[i*2];
      float4 b2 = ((const float4*)outW)[i*2+1];
      uint4 o;
      o.x = pkh(a.x,a.y); o.y = pkh(a.z,a.w);
      o.z = pkh(b2.x,b2.y); o.w = pkh(b2.z,b2.w);
      ((uint4*)outW16)[i] = o;
    }
    return;
  }
  int dir = blockIdx.x >> 5, b = blockIdx.x & 31;
  int jj = threadIdx.x;
  const _Float16* gi = dir ? gi16_b : gi16_f;
  const uint4* Wi8p = (dir ? Wi8_b : Wi8_f) + jj;
  float scl = scl_i8[dir*H3 + jj];
  float bh = (dir ? bhh_b : bhh_f)[jj];

  __shared__ __align__(16) unsigned h8u[HDIM/4];   // i8-packed h*127 (256 B)
  __shared__ __align__(16) float st[H3];
  __shared__ uint4 Wlds[8][H3];                    // i8 pairchunks 0..7 (98304 B)

  #pragma unroll
  for (int p=0;p<8;++p) Wlds[p][jj] = Wi8p[p*H3];

  if (jj < HDIM/4) h8u[jj] = 0u;
  float hreg = 0.f;
  _Float16* dst = enc16 + (size_t)b*2*HDIM + dir*HDIM + jj;
  __syncthreads();

  for (int s=0;s<SLEN;++s){
    const _Float16* grow = gi + ((size_t)s*BATCH + b)*H3;
    float g1 = 0.f, g2 = 0.f;
    if (jj < 512)  g1 = (float)grow[jj];
    if (jj < HDIM) g2 = (float)grow[2*HDIM + jj];
    int is0=0, is1=0, is2=0, is3=0;
    #pragma unroll
    for (int p=0;p<8;++p){
      uint4 w = Wlds[p][jj];
      uint4 hq = *(const uint4*)&h8u[4*p];
      is0 = sdot4(w.x, hq.x, is0);
      is1 = sdot4(w.y, hq.y, is1);
      is2 = sdot4(w.z, hq.z, is2);
      is3 = sdot4(w.w, hq.w, is3);
    }
    #pragma unroll
    for (int p=8;p<16;++p){
      uint4 w = Wi8p[(size_t)p*H3];
      uint4 hq = *(const uint4*)&h8u[4*p];
      is0 = sdot4(w.x, hq.x, is0);
      is1 = sdot4(w.y, hq.y, is1);
      is2 = sdot4(w.z, hq.z, is2);
      is3 = sdot4(w.w, hq.w, is3);
    }
    float acc = (float)((is0+is1)+(is2+is3))*scl + bh;
    st[jj] = (jj < 512) ? (acc + g1) : acc;
    __syncthreads();
    if (jj < HDIM){
      float rr = fsig(st[jj]);
      float zz = fsig(st[HDIM + jj]);
      float nn = ftanh(g2 + rr*st[2*HDIM + jj]);
      float h2v = nn + zz*(hreg - nn);
      hreg = h2v;
      int srow = dir ? (SLEN-1-s) : s;
      dst[(size_t)srow*BATCH*2*HDIM] = (_Float16)h2v;
      int iv = (int)rintf(h2v*127.f);
      iv = iv > 127 ? 127 : (iv < -127 ? -127 : iv);
      ((char*)h8u)[jj] = (char)iv;
      if (s == SLEN-1) hfin[(size_t)(dir*BATCH + b)*HDIM + jj] = h2v;
    }
    __syncthreads();
  }
}

// ---------- bridge: h0 = tanh([hf,hb] @ bridge_W.T + b) ----------
__global__ __launch_bounds__(256) void k_bridge(
    const float* __restrict__ hfin,
    const float* __restrict__ bridge_W, const float* __restrict__ bridge_b,
    float* __restrict__ h_out)
{
  int b = blockIdx.x, j = threadIdx.x;
  __shared__ float hcat[2*HDIM];
  hcat[j]        = hfin[(size_t)b*HDIM + j];
  hcat[HDIM + j] = hfin[(size_t)(BATCH + b)*HDIM + j];
  __syncthreads();
  const float* w = bridge_W + (size_t)j*2*HDIM;
  float4 a = {0.f,0.f,0.f,0.f};
  #pragma unroll 4
  for (int k=0;k<2*HDIM;k+=4){
    float4 h4 = *(const float4*)&hcat[k];
    float4 w4 = *(const float4*)&w[k];
    a.x=fmaf(h4.x,w4.x,a.x); a.y=fmaf(h4.y,w4.y,a.y);
    a.z=fmaf(h4.z,w4.z,a.z); a.w=fmaf(h4.w,w4.w,a.w);
  }
  h_out[b*HDIM+j] = ftanh((a.x+a.y)+(a.z+a.w) + bridge_b[j]);
}

// ---------- decoder step part B: q + attention scores + e + partial sums/ctx ----------
__global__ __launch_bounds__(256) void k_attnB(
    int t,
    const _Float16* __restrict__ proj16,
    const _Float16* __restrict__ enc16,
    const uint4* __restrict__ Wq16k,
    const float* __restrict__ attn_We,
    const float* __restrict__ hin,
    float* __restrict__ alphas_e,
    float* __restrict__ sum_part,
    float* __restrict__ ctx_part)
{
  int ch = blockIdx.x, b = blockIdx.y;
  int tid = threadIdx.x;
  __shared__ float q_s[HDIM], we_s[HDIM], sc[SCHUNK], red[8];
  __shared__ __align__(16) unsigned hq[HDIM/2];

  we_s[tid] = attn_We[tid];
  if (tid < HDIM/2){
    float2 hv = *(const float2*)&hin[b*HDIM + tid*2];
    hq[tid] = pkh(hv.x, hv.y);
  }
  __syncthreads();
  {
    float a0=0.f,a1=0.f,a2=0.f,a3=0.f;
    #pragma unroll
    for (int k8=0;k8<32;++k8){
      uint4 w = Wq16k[(size_t)k8*HDIM + tid];
      uint4 hp = *(const uint4*)&hq[k8*4];
      a0 = fdot2h(u2h(w.x),u2h(hp.x),a0);
      a1 = fdot2h(u2h(w.y),u2h(hp.y),a1);
      a2 = fdot2h(u2h(w.z),u2h(hp.z),a2);
      a3 = fdot2h(u2h(w.w),u2h(hp.w),a3);
    }
    q_s[tid] = (a0+a1)+(a2+a3);
  }
  __syncthreads();
  {
    int wave = tid >> 6, lane = tid & 63;
    int d0 = lane*4;
    float4 qv = *(const float4*)&q_s[d0];
    float4 wv = *(const float4*)&we_s[d0];
    for (int is = wave; is < SCHUNK; is += 4){
      int s = ch*SCHUNK + is;
      uint2 p = *(const uint2*)&proj16[((size_t)(s*BATCH + b))*HDIM + d0];
      h2 pa = u2h(p.x), pb = u2h(p.y);
      float v = ftanh(qv.x+(float)pa.x)*wv.x + ftanh(qv.y+(float)pa.y)*wv.y
              + ftanh(qv.z+(float)pb.x)*wv.z + ftanh(qv.w+(float)pb.y)*wv.w;
      v = wred_sum(v);
      if (lane == 0){
        float e = __expf(v);
        sc[is] = e;
        alphas_e[((size_t)t*SLEN + s)*BATCH + b] = e;
      }
    }
  }
  __syncthreads();
  {
    float sv = (tid < SCHUNK) ? sc[tid] : 0.f;
    sv = block_sum(sv, red);
    if (tid == 0) sum_part[b*8 + ch] = sv;
  }
  {
    float a0=0.f, a1=0.f;
    for (int is=0; is<SCHUNK; ++is){
      int s = ch*SCHUNK + is;
      unsigned u = *(const unsigned*)&enc16[((size_t)(s*BATCH + b) << 9) + tid*2];
      h2 ev = u2h(u);
      float e = sc[is];
      a0 = fmaf(e, (float)ev.x, a0);
      a1 = fmaf(e, (float)ev.y, a1);
    }
    float2 o; o.x = a0; o.y = a1;
    *(float2*)&ctx_part[(((size_t)b*8 + ch) << 9) + tid*2] = o;
  }
}

// ---------- decoder step part D: ctx reduce + GRU + h/cat writes ----------
__global__ __launch_bounds__(256) void k_gruD(
    int t,
    const float* __restrict__ ctx_part,
    const float* __restrict__ sum_part,
    const float* __restrict__ gie_all,
    const uint4* __restrict__ dWck16,
    const uint4* __restrict__ dWhk16,
    const float* __restrict__ dec_bhh,
    const float* __restrict__ hin,
    float* __restrict__ hout,
    float* __restrict__ cat_all, _Float16* __restrict__ cat16,
    float* __restrict__ sums_all)
{
  int ch = blockIdx.x, b = blockIdx.y;
  int tid = threadIdx.x;
  int jl = tid & 31, slice = tid >> 5;
  __shared__ __align__(16) unsigned cpk[HDIM], hpk[HDIM/2];
  __shared__ float hf[HDIM];
  __shared__ float pc[3][8][32], ph[3][8][32];
  __shared__ float invs;

  if (tid == 0){
    float ssum = 0.f;
    #pragma unroll
    for (int c=0;c<8;++c) ssum += sum_part[b*8 + c];
    float inv = 1.f/ssum;
    invs = inv;
    if (ch == 0) sums_all[t*BATCH + b] = inv;
  }
  if (tid < HDIM/2){
    float2 hv = *(const float2*)&hin[b*HDIM + tid*2];
    hpk[tid] = pkh(hv.x, hv.y);
    hf[tid*2] = hv.x; hf[tid*2+1] = hv.y;
  }
  __syncthreads();
  {
    int d0 = tid*2;
    float c0=0.f, c1=0.f;
    #pragma unroll
    for (int c=0;c<8;++c){
      float2 v = *(const float2*)&ctx_part[(((size_t)b*8 + c) << 9) + d0];
      c0 += v.x; c1 += v.y;
    }
    c0 *= invs; c1 *= invs;
    cpk[tid] = pkh(c0, c1);
    if (ch == 0){
      int r = t*BATCH + b;
      cat_all[(size_t)r*896 + 384 + d0]     = c0;
      cat_all[(size_t)r*896 + 384 + d0 + 1] = c1;
      cat16[(size_t)r*896 + 384 + d0]     = (_Float16)c0;
      cat16[(size_t)r*896 + 384 + d0 + 1] = (_Float16)c1;
    }
  }
  __syncthreads();
  {
    int jb = ch*32 + jl;
    float c0=0.f,c1=0.f,c2=0.f, g0=0.f,g1=0.f,g2=0.f;
    #pragma unroll
    for (int i=0;i<8;++i){
      int k8 = slice*8 + i;
      uint4 hq = *(const uint4*)&cpk[k8*4];
      uint4 w0 = dWck16[(size_t)k8*H3 + jb];
      uint4 w1 = dWck16[(size_t)k8*H3 + 256 + jb];
      uint4 w2 = dWck16[(size_t)k8*H3 + 512 + jb];
      c0 = fdot2h(u2h(w0.x),u2h(hq.x),c0); c0 = fdot2h(u2h(w0.y),u2h(hq.y),c0);
      c0 = fdot2h(u2h(w0.z),u2h(hq.z),c0); c0 = fdot2h(u2h(w0.w),u2h(hq.w),c0);
      c1 = fdot2h(u2h(w1.x),u2h(hq.x),c1); c1 = fdot2h(u2h(w1.y),u2h(hq.y),c1);
      c1 = fdot2h(u2h(w1.z),u2h(hq.z),c1); c1 = fdot2h(u2h(w1.w),u2h(hq.w),c1);
      c2 = fdot2h(u2h(w2.x),u2h(hq.x),c2); c2 = fdot2h(u2h(w2.y),u2h(hq.y),c2);
      c2 = fdot2h(u2h(w2.z),u2h(hq.z),c2); c2 = fdot2h(u2h(w2.w),u2h(hq.w),c2);
    }
    #pragma unroll
    for (int i=0;i<4;++i){
      int k8 = slice*4 + i;
      uint4 hq = *(const uint4*)&hpk[k8*4];
      uint4 w0 = dWhk16[(size_t)k8*H3 + jb];
      uint4 w1 = dWhk16[(size_t)k8*H3 + 256 + jb];
      uint4 w2 = dWhk16[(size_t)k8*H3 + 512 + jb];
      g0 = fdot2h(u2h(w0.x),u2h(hq.x),g0); g0 = fdot2h(u2h(w0.y),u2h(hq.y),g0);
      g0 = fdot2h(u2h(w0.z),u2h(hq.z),g0); g0 = fdot2h(u2h(w0.w),u2h(hq.w),g0);
      g1 = fdot2h(u2h(w1.x),u2h(hq.x),g1); g1 = fdot2h(u2h(w1.y),u2h(hq.y),g1);
      g1 = fdot2h(u2h(w1.z),u2h(hq.z),g1); g1 = fdot2h(u2h(w1.w),u2h(hq.w),g1);
      g2 = fdot2h(u2h(w2.x),u2h(hq.x),g2); g2 = fdot2h(u2h(w2.y),u2h(hq.y),g2);
      g2 = fdot2h(u2h(w2.z),u2h(hq.z),g2); g2 = fdot2h(u2h(w2.w),u2h(hq.w),g2);
    }
    pc[0][slice][jl]=c0; pc[1][slice][jl]=c1; pc[2][slice][jl]=c2;
    ph[0][slice][jl]=g0; ph[1][slice][jl]=g1; ph[2][slice][jl]=g2;
  }
  __syncthreads();
  if (tid < 32){
    int j = tid, r = t*BATCH + b;
    int jj = ch*32 + j;
    float gi0 = gie_all[(size_t)r*H3 + jj];
    float gi1 = gie_all[(size_t)r*H3 + 256 + jj];
    float gi2 = gie_all[(size_t)r*H3 + 512 + jj];
    float gh0 = dec_bhh[jj], gh1 = dec_bhh[256 + jj], gh2 = dec_bhh[512 + jj];
    #pragma unroll
    for (int c=0;c<8;++c){
      gi0 += pc[0][c][j]; gi1 += pc[1][c][j]; gi2 += pc[2][c][j];
      gh0 += ph[0][c][j]; gh1 += ph[1][c][j]; gh2 += ph[2][c][j];
    }
    float rr = fsig(gi0 + gh0);
    float zz = fsig(gi1 + gh1);
    float nn = ftanh(gi2 + rr*gh2);
    float hp = hf[jj];
    float h2v = nn + zz*(hp - nn);
    hout[b*HDIM + jj] = h2v;
    cat_all[(size_t)r*896 + 128 + jj] = h2v;
    cat16[(size_t)r*896 + 128 + jj] = (_Float16)h2v;
  }
}

// ---------- p_gen = sigmoid(cat . pgen_W + b) ----------
__global__ __launch_bounds__(64) void k_pgen(
    const float* __restrict__ cat_all,
    const float* __restrict__ pgen_W, const float* __restrict__ pgen_b,
    float* __restrict__ pgen_all)
{
  int r = blockIdx.x;
  const float* c = cat_all + (size_t)r*896;
  float acc = 0.f;
  for (int k=threadIdx.x; k<896; k+=64) acc = fmaf(c[k], pgen_W[k], acc);
  acc = wred_sum(acc);
  if (threadIdx.x==0) pgen_all[r] = fsig(acc + pgen_b[0]);
}

// ---------- single-pass sum of exp over V (no max: |logits| < ~1) ----------
__global__ __launch_bounds__(256) void k_rowsum(
    const _Float16* __restrict__ logits, float* __restrict__ row_sum)
{
  int r = blockIdx.x;
  const uint4* row = (const uint4*)(logits + (size_t)r*VVOC);
  __shared__ float red[8];
  float s = 0.f;
  for (int v=threadIdx.x; v<VVOC/8; v+=256){
    uint4 x = row[v];
    h2 a=u2h(x.x), bb=u2h(x.y), c=u2h(x.z), d=u2h(x.w);
    s += __expf((float)a.x) + __expf((float)a.y) + __expf((float)bb.x) + __expf((float)bb.y)
       + __expf((float)c.x) + __expf((float)c.y) + __expf((float)d.x) + __expf((float)d.y);
  }
  s = block_sum(s, red);
  if (threadIdx.x==0) row_sum[r] = 1.f/s;
}

// ---------- scatter copy-distribution into zeroed out (linear domain) ----------
__global__ __launch_bounds__(512) void k_scatter(
    const int* __restrict__ input_seq_ext,
    const float* __restrict__ alphas_e, const float* __restrict__ sums_all,
    const float* __restrict__ pgen_all,
    float* __restrict__ out)
{
  int r = blockIdx.x;               // t*32+b
  int s = threadIdx.x;
  if (s >= SLEN) return;
  int t = r >> 5, b = r & 31;
  float w = (1.f - pgen_all[r]) * alphas_e[((size_t)t*SLEN + s)*BATCH + b] * sums_all[r];
  int idx = input_seq_ext[b*SLEN + s];
  atomicAdd(&out[((size_t)(t+1)*BATCH + b)*VEXT + idx], w);
}

// ---------- fused final: out = log(copy + gen + 1e-12), t in [1,16) ----------
__global__ __launch_bounds__(256) void k_final2(
    const _Float16* __restrict__ logits, const float* __restrict__ pgen_all,
    const float* __restrict__ row_sum,
    float* __restrict__ out)
{
  int v = blockIdx.x*256 + threadIdx.x;
  if (v >= VEXT) return;
  int b = blockIdx.y, t = blockIdx.z + 1;
  size_t o = ((size_t)t*BATCH + b)*VEXT + v;
  int r = (t-1)*BATCH + b;
  float val = out[o] + 1e-12f;      // copy mass from k_scatter (0 elsewhere)
  if (v < VVOC)
    val += pgen_all[r] * row_sum[r] * __expf((float)logits[(size_t)r*VVOC + v]);
  out[o] = __logf(val);
}

extern "C" void kernel_launch(void* const* d_in, const int* in_sizes, int n_in,
                              void* d_out, int out_size, void* d_ws, size_t ws_size,
                              hipStream_t stream)
{
  (void)in_sizes; (void)n_in; (void)ws_size;
  const int*   input_seq     = (const int*)d_in[0];
  const int*   input_seq_ext = (const int*)d_in[1];
  const int*   target_seq    = (const int*)d_in[2];
  const float* embedding     = (const float*)d_in[3];
  const float* enc_Wih_f     = (const float*)d_in[4];
  const float* enc_Whh_f     = (const float*)d_in[5];
  const float* enc_bih_f     = (const float*)d_in[6];
  const float* enc_bhh_f     = (const float*)d_in[7];
  const float* enc_Wih_b     = (const float*)d_in[8];
  const float* enc_Whh_b     = (const float*)d_in[9];
  const float* enc_bih_b     = (const float*)d_in[10];
  const float* enc_bhh_b     = (const float*)d_in[11];
  const float* proj_W        = (const float*)d_in[12];
  const float* proj_b        = (const float*)d_in[13];
  const float* bridge_W      = (const float*)d_in[14];
  const float* bridge_b      = (const float*)d_in[15];
  const float* dec_Wih       = (const float*)d_in[16];
  const float* dec_Whh       = (const float*)d_in[17];
  const float* dec_bih       = (const float*)d_in[18];
  const float* dec_bhh       = (const float*)d_in[19];
  const float* attn_Wq       = (const float*)d_in[20];
  const float* attn_We       = (const float*)d_in[21];
  const float* lin_W         = (const float*)d_in[22];
  const float* lin_b         = (const float*)d_in[23];
  const float* pgen_W        = (const float*)d_in[24];
  const float* pgen_b        = (const float*)d_in[25];
  const float* out_W         = (const float*)d_in[26];
  const float* out_b         = (const float*)d_in[27];
  float* out = (float*)d_out;
  float* ws  = (float*)d_ws;

  // ---- workspace layout (float offsets); ~146 MB
  _Float16* emb16    = (_Float16*)(ws + 0);            // 409600 f
  _Float16* Wih16_f  = (_Float16*)(ws + 409600);       // 49152 f
  _Float16* Wih16_b  = (_Float16*)(ws + 458752);       // 49152 f
  _Float16* proj_W16 = (_Float16*)(ws + 507904);       // 65536 f
  _Float16* lin_W16  = (_Float16*)(ws + 573440);       // 114688 f
  _Float16* cat16    = (_Float16*)(ws + 688128);       // 215040 f
  _Float16* lin16    = (_Float16*)(ws + 903168);       // 61440 f
  _Float16* dWih16   = (_Float16*)(ws + 964608);       // 245760 f -> 1210368
  _Float16* enc16    = (_Float16*)(ws + 1638400);      // 3276800 f
  float* hfin        = ws + 4915200;                   // 16384 f
  _Float16* proj16   = (_Float16*)(ws + 8192000);      // 1638400 f
  _Float16* gi16_f   = (_Float16*)(ws + 11468800);     // 4915200 f [dies after k_enc]
  _Float16* gi16_b   = (_Float16*)(ws + 16384000);     // 4915200 f [dies after k_enc]
  _Float16* logits16 = (_Float16*)(ws + 11468800);     // 6000000 f (post-enc, overlaps gi)
  _Float16* out_W16  = (_Float16*)(ws + 23468800);     // 6400000 f
  uint4* Wq16k       = (uint4*)(ws + 33145600);        // 32768 f
  uint4* dWck16      = (uint4*)(ws + 33178368);        // 196608 f
  uint4* dWhk16      = (uint4*)(ws + 33374976);        // 98304 f
  float* ctx_part    = ws + 33473280;                  // 131072 f
  float* sum_part    = ws + 33604352;                  // 256 f
  float* sums_all    = ws + 33604608;                  // 480 f
  float* hbuf0       = ws + 33605088;                  // 8192 f
  float* hbuf1       = ws + 33613280;                  // 8192 f -> 33621472
  uint4* Wi8_f       = (uint4*)(ws + 33621472);        // 49152 f (16 i8 pairchunks, dir f)
  uint4* Wi8_b       = (uint4*)(ws + 33670624);        // 49152 f
  float* scl_i8      = ws + 33719776;                  // 1536 f -> 33721312
  float* cat_all     = ws + 35468800;                  // 430080
  float* gie_all     = ws + 35898880;                  // 368640
  float* alphas_e    = ws + 36275712;                  // 192000
  float* pgen_all    = ws + 36467712;                  // 480
  float* row_sum     = ws + 36468192;                  // 480

  // zero the output early (t=0 rows stay 0; scatter accumulates into zeros)
  (void)hipMemsetAsync(out, 0, (size_t)out_size*sizeof(float), stream);

  k_embed<<<dim3(SLEN*BATCH + NDEC*BATCH), dim3(64), 0, stream>>>(
      input_seq, target_seq, embedding, emb16, cat_all, cat16);

  // batched weight conversions
  k_cvtv5<<<dim3(240, 5), dim3(256), 0, stream>>>(
      enc_Wih_f, Wih16_f, 12288,
      enc_Wih_b, Wih16_b, 12288,
      proj_W,    proj_W16, 16384,
      lin_W,     lin_W16,  28672,
      dec_Wih,   dWih16,   61440);
  k_cvtk3<<<dim3(H3, 3), dim3(64), 0, stream>>>(
      dec_Wih,   dWck16,
      dec_Whh,   dWhk16,
      attn_Wq,   Wq16k);
  k_cvti8<<<dim3(H3, 2), dim3(64), 0, stream>>>(enc_Whh_f, Wi8_f, enc_Whh_b, Wi8_b, scl_i8);

  // gi (f16) = emb @ Wih.T + bih (MFMA)
  k_gmm<<<dim3(6,100), dim3(256), 0, stream>>>(emb16, EDIM, Wih16_f, EDIM, enc_bih_f,
      (float*)nullptr, gi16_f, H3, SLEN*BATCH, H3, EDIM, 0);
  k_gmm<<<dim3(6,100), dim3(256), 0, stream>>>(emb16, EDIM, Wih16_b, EDIM, enc_bih_b,
      (float*)nullptr, gi16_b, H3, SLEN*BATCH, H3, EDIM, 1);

  // k_enc: 64 recurrence blocks + 200 conversion blocks (out_W -> f16 on idle CUs)
  k_enc<<<dim3(264), dim3(768), 0, stream>>>(gi16_f, gi16_b, Wi8_f, Wi8_b,
      scl_i8, enc_bhh_f, enc_bhh_b, enc16, hfin, out_W, out_W16);

  // proj (f16) = enc16 @ proj_W.T + proj_b
  k_gmm<<<dim3(2,100), dim3(256), 0, stream>>>(enc16, 2*HDIM, proj_W16, 2*HDIM, proj_b,
      (float*)nullptr, proj16, HDIM, SLEN*BATCH, HDIM, 2*HDIM, 0);

  k_bridge<<<dim3(BATCH), dim3(256), 0, stream>>>(hfin, bridge_W, bridge_b, hbuf0);

  // decoder-embedding gate contributions (K=128 e-cols of cat), MFMA
  k_gmm<<<dim3(6,4), dim3(256), 0, stream>>>(cat16, 896, dWih16, 640, dec_bih,
      gie_all, (_Float16*)nullptr, H3, NDEC*BATCH, H3, EDIM, 0);

  // 15 decoder steps: 2 wide kernels per step, h ping-pong
  float* hb[2] = {hbuf0, hbuf1};
  for (int t=0;t<NDEC;++t){
    k_attnB<<<dim3(8,32), dim3(256), 0, stream>>>(t, proj16, enc16, Wq16k, attn_We,
        hb[t&1], alphas_e, sum_part, ctx_part);
    k_gruD<<<dim3(8,32), dim3(256), 0, stream>>>(t, ctx_part, sum_part, gie_all,
        dWck16, dWhk16, dec_bhh, hb[t&1], hb[(t+1)&1], cat_all, cat16, sums_all);
  }

  // epilogue
  k_gmm<<<dim3(2,4), dim3(256), 0, stream>>>(cat16, 896, lin_W16, 896, lin_b,
      (float*)nullptr, lin16, HDIM, NDEC*BATCH, HDIM, 896, 0);
  k_pgen<<<dim3(NDEC*BATCH), dim3(64), 0, stream>>>(cat_all, pgen_W, pgen_b, pgen_all);
  k_gmm<<<dim3(391,4), dim3(256), 0, stream>>>(lin16, HDIM, out_W16, HDIM, out_b,
      (float*)nullptr, logits16, VVOC, NDEC*BATCH, VVOC, HDIM, 0);
  k_rowsum<<<dim3(NDEC*BATCH), dim3(256), 0, stream>>>(logits16, row_sum);
  k_scatter<<<dim3(NDEC*BATCH), dim3(512), 0, stream>>>(input_seq_ext, alphas_e, sums_all, pgen_all, out);
  k_final2<<<dim3(196, BATCH, NDEC), dim3(256), 0, stream>>>(logits16, pgen_all, row_sum, out);
}